// Round 15
// baseline (86.212 us; speedup 1.0000x reference)
//
#include <hip/hip_runtime.h>
#include <math.h>

// AWLoss closed-form: f = 24 - (0.5/511^2) * sum_c S1_c^2 / S2_c
// S1 = sum wgt*Re(F), S2 = sum wgt*|F|^2 over half-spectrum k1 in [0,511),
// k2 in [0,256), wgt = 1 for k2==0 else 2, F = conj(X)Y / |X|^2
// (1e-9 pre-whitening is < 1e-12 relative to |X|^2 ~ 1e4 -> dropped).
// X = DFT2(pad(target)), Y = DFT2(pad(recon)), pad offset 127.
//
// Round-15 stage2: LOW-PRESSURE wave decomposition. R6-R14 all demanded ~220
// VGPR/wave (2-kt twiddles + acc) and the allocator silently capped at 128,
// re-loading twiddles in-loop (R12 vs R13 totals prove the "fast" variant ran
// ~42us like the spilling one). New wave-task = (ch, t, kt-quarter): x1t frags
// stationary in 64 VGPR, twiddles streamed via double-buffered LDS (16KB/kt
// tile, global_load_lds, shared by the 4 waves). ~116 VGPR total. 768 blocks.
// stage1/setup: exact R12 (best total).

#define NCH 48
#define PADOFF 127
#define TWO_PI_F 6.283185307179586f

typedef float f32x4 __attribute__((ext_vector_type(4)));
typedef short s16x8 __attribute__((ext_vector_type(8)));
typedef unsigned short u16;

typedef __attribute__((address_space(1))) const unsigned char* gas_p;
typedef __attribute__((address_space(3))) unsigned char* las_p;

union frag_u { u16 u[8]; s16x8 v; };

__device__ __forceinline__ u16 f2bf(float f) {
    union { float f; unsigned u; } x; x.f = f;
    unsigned r = x.u + 0x7FFFu + ((x.u >> 16) & 1u);
    return (u16)(r >> 16);
}

#define MFMA16(A, B, C) __builtin_amdgcn_mfma_f32_16x16x32_bf16(A, B, C, 0, 0, 0)

// ---------------- setup: twiddle fragment table + acc zero ----------------
// w2f : fragments [kt(32)][c(2)][kk(8)][lane(64)][j(8)] bf16
//       element: tw((16kt + (l&15)) * (32kk + 8(l>>4) + j + 127) mod 511),
//       c=0 cos, c=1 sin; rows k1>=511 zeroed.
__global__ __launch_bounds__(256) void setup(u16* __restrict__ w2f,
                                             float* __restrict__ sacc) {
    __shared__ float cs[511], sn[511];
    int tid = threadIdx.x;
    for (int i = tid; i < 511; i += 256) {
        float a = -TWO_PI_F * (float)i / 511.0f;
        cs[i] = cosf(a);
        sn[i] = sinf(a);
    }
    __syncthreads();

    int i = blockIdx.x * 256 + tid;      // i < 262144
    int j = i & 7, l = (i >> 3) & 63, kk = (i >> 9) & 7;
    int c = (i >> 12) & 1, kt = i >> 13;
    int k1 = 16 * kt + (l & 15);
    u16 v = 0;
    if (k1 < 511) {
        int n = 32 * kk + 8 * (l >> 4) + j;
        int p = (k1 * (n + PADOFF)) % 511;
        v = f2bf(c ? sn[p] : cs[p]);
    }
    w2f[i] = v;
    if (blockIdx.x == 0 && tid < 2 * NCH) sacc[tid] = 0.0f;
}

// ---------------- stage 1: DFT along W (exact R12 version) ----------------
__global__ __launch_bounds__(256, 2) void stage1(const float* __restrict__ target,
                                                 const float* __restrict__ recon,
                                                 const u16* __restrict__ w2f,
                                                 u16* __restrict__ x1t,
                                                 int c0) {
    int tid = threadIdx.x;
    int w = tid >> 6, l = tid & 63;
    int lm = l & 15, lh = l >> 4;
    int h   = blockIdx.x & 1;
    int q   = (blockIdx.x >> 1) & 3;
    int imgl = blockIdx.x >> 3;          // [0, 2cc)
    int lc = imgl >> 1;
    int tsel = imgl & 1;
    const float* src = (tsel == 0 ? target : recon) + (size_t)(c0 + lc) * 65536;
    int r0 = 64 * q;

    __shared__ u16 lin[16384];           // 32 KiB: [(s*8+kk)*512 + l*8]

    {
        int row = tid >> 2;              // 0..63
        int cg  = tid & 3;
        const float* rp = src + (size_t)(r0 + row) * 256 + cg * 64;
        float4 v[16];
        #pragma unroll
        for (int i = 0; i < 16; ++i) v[i] = *(const float4*)(rp + 4 * i);
        u16 b[64];
        #pragma unroll
        for (int i = 0; i < 16; ++i) {
            b[4*i]   = f2bf(v[i].x); b[4*i+1] = f2bf(v[i].y);
            b[4*i+2] = f2bf(v[i].z); b[4*i+3] = f2bf(v[i].w);
        }
        int s = row >> 4, lmw = row & 15;
        #pragma unroll
        for (int i2 = 0; i2 < 8; ++i2) {
            int col0 = cg * 64 + i2 * 8;
            int kk = col0 >> 5, lhw = (col0 >> 3) & 3;
            u16* dst = &lin[((s * 8 + kk) * 512) + (lhw * 16 + lmw) * 8];
            *(s16x8*)dst = *(const s16x8*)&b[i2 * 8];
        }
    }

    int t0 = 8 * h + 2 * w;
    s16x8 tw00[8], tw01[8], tw10[8], tw11[8];
    {
        const u16* p0 = w2f + (size_t)t0 * 8192 + l * 8;
        const u16* p1 = w2f + (size_t)(t0 + 1) * 8192 + l * 8;
        #pragma unroll
        for (int kk = 0; kk < 8; ++kk) {
            tw00[kk] = *(const s16x8*)(p0 + kk * 512);
            tw01[kk] = *(const s16x8*)(p0 + 4096 + kk * 512);
            tw10[kk] = *(const s16x8*)(p1 + kk * 512);
            tw11[kk] = *(const s16x8*)(p1 + 4096 + kk * 512);
        }
    }
    __syncthreads();

    f32x4 a00[4], a01[4], a10[4], a11[4];
    #pragma unroll
    for (int s = 0; s < 4; ++s) {
        a00[s] = (f32x4){0,0,0,0}; a01[s] = (f32x4){0,0,0,0};
        a10[s] = (f32x4){0,0,0,0}; a11[s] = (f32x4){0,0,0,0};
    }
    #pragma unroll
    for (int kk = 0; kk < 8; ++kk) {
        s16x8 af[4];
        #pragma unroll
        for (int s = 0; s < 4; ++s)
            af[s] = *(const s16x8*)&lin[((s * 8 + kk) * 512) + l * 8];
        #pragma unroll
        for (int s = 0; s < 4; ++s) {
            a00[s] = MFMA16(af[s], tw00[kk], a00[s]);
            a01[s] = MFMA16(af[s], tw01[kk], a01[s]);
            a10[s] = MFMA16(af[s], tw10[kk], a10[s]);
            a11[s] = MFMA16(af[s], tw11[kk], a11[s]);
        }
    }

    u16* chdst = x1t + (size_t)(lc * 4 + tsel * 2) * 65536;
    #pragma unroll
    for (int s = 0; s < 4; ++s) {
        size_t off0 = (size_t)(16 * t0 + lm) * 256 + r0 + 16 * s + 4 * lh;
        size_t off1 = off0 + 4096;
        ushort4 o;
        o.x = f2bf(a00[s][0]); o.y = f2bf(a00[s][1]);
        o.z = f2bf(a00[s][2]); o.w = f2bf(a00[s][3]);
        *(ushort4*)(chdst + off0) = o;
        o.x = f2bf(a01[s][0]); o.y = f2bf(a01[s][1]);
        o.z = f2bf(a01[s][2]); o.w = f2bf(a01[s][3]);
        *(ushort4*)(chdst + 65536 + off0) = o;
        o.x = f2bf(a10[s][0]); o.y = f2bf(a10[s][1]);
        o.z = f2bf(a10[s][2]); o.w = f2bf(a10[s][3]);
        *(ushort4*)(chdst + off1) = o;
        o.x = f2bf(a11[s][0]); o.y = f2bf(a11[s][1]);
        o.z = f2bf(a11[s][2]); o.w = f2bf(a11[s][3]);
        *(ushort4*)(chdst + 65536 + off1) = o;
    }
}

// ---------------- stage 2: x1t-frag-stationary (64 VGPR), twiddles via LDS ----------------
// grid = cc*16 blocks x 256 thr: ktq = bid&3, grp = bid>>2; wave task =
// grp*4 + w -> (lc = task>>4, t = task&15). Wave loops the 8 kt of its
// quarter; twiddle tiles (16KB) double-buffered in LDS, shared by 4 waves.
__global__ __launch_bounds__(256) void stage2(const u16* __restrict__ x1t,
                                              const u16* __restrict__ w2f,
                                              float* __restrict__ sacc,
                                              int c0, int cc) {
    int tid = threadIdx.x;
    int w = tid >> 6, l = tid & 63;
    int lm = l & 15, lh = l >> 4;
    int ktq = blockIdx.x & 3;
    int grp = blockIdx.x >> 2;
    int task = grp * 4 + w;             // [0, cc*16)
    int lc = task >> 4;
    int t  = task & 15;

    __shared__ u16 twA[8192];           // 16 KiB each: [c][kk][lane][8]
    __shared__ u16 twB[8192];

    // stationary x1t fragments: 16 x s16x8 = 64 VGPR, loaded once (L3-hot)
    const u16* base = x1t + (size_t)(4 * lc) * 65536;
    int roff = (16 * t + lm) * 256 + 8 * lh;
    s16x8 ar[8], ai[8], br[8], bi[8];
    #pragma unroll
    for (int kk = 0; kk < 8; ++kk) {
        int off = roff + 32 * kk;
        ar[kk] = *(const s16x8*)(base + off);
        ai[kk] = *(const s16x8*)(base + 65536 + off);
        br[kk] = *(const s16x8*)(base + 131072 + off);
        bi[kk] = *(const s16x8*)(base + 196608 + off);
    }

    int k2 = 16 * t + lm;
    float wgt = (k2 == 0) ? 1.f : 2.f;
    float s1 = 0.f, s2 = 0.f;
    int kt0 = 8 * ktq;

#define STAGE_TW(BUF, KT) do {                                                \
    const u16* gt_ = w2f + (size_t)(KT) * 8192 + (size_t)(w * 64 + l) * 8;    \
    _Pragma("unroll")                                                         \
    for (int q_ = 0; q_ < 4; ++q_) {                                          \
        __builtin_amdgcn_global_load_lds((gas_p)(gt_ + q_ * 2048),            \
            (las_p)&BUF[(q_ * 256 + w * 64) * 8], 16, 0, 0);                  \
    } } while (0)

#define COMPUTE(BUF, KT) do {                                                 \
    f32x4 crr = {0,0,0,0}, cii = {0,0,0,0}, cri = {0,0,0,0}, cir = {0,0,0,0}; \
    f32x4 drr = {0,0,0,0}, dii = {0,0,0,0}, dri = {0,0,0,0}, dir = {0,0,0,0}; \
    _Pragma("unroll")                                                         \
    for (int kk = 0; kk < 8; ++kk) {                                          \
        s16x8 wr = *(const s16x8*)&BUF[kk * 512 + l * 8];                     \
        s16x8 wi = *(const s16x8*)&BUF[4096 + kk * 512 + l * 8];              \
        crr = MFMA16(wr, ar[kk], crr);                                        \
        cii = MFMA16(wi, ai[kk], cii);                                        \
        cri = MFMA16(wr, ai[kk], cri);                                        \
        cir = MFMA16(wi, ar[kk], cir);                                        \
        drr = MFMA16(wr, br[kk], drr);                                        \
        dii = MFMA16(wi, bi[kk], dii);                                        \
        dri = MFMA16(wr, bi[kk], dri);                                        \
        dir = MFMA16(wi, br[kk], dir);                                        \
    }                                                                         \
    _Pragma("unroll")                                                         \
    for (int r = 0; r < 4; ++r) {                                             \
        int k1 = 16 * (KT) + 4 * lh + r;                                      \
        float wg2 = (k1 < 511) ? wgt : 0.f;                                   \
        float Xr = crr[r] - cii[r], Xi = cri[r] + cir[r];                     \
        float Yr = drr[r] - dii[r], Yi = dri[r] + dir[r];                     \
        float Pr = Xr * Yr + Xi * Yi;                                         \
        float Pi = Xr * Yi - Xi * Yr;                                         \
        float Q  = Xr * Xr + Xi * Xi;                                         \
        float inv = 1.0f / (Q * Q + 1e-30f);                                  \
        s1 += wg2 * Pr * Q * inv;                                             \
        s2 += wg2 * (Pr * Pr + Pi * Pi) * inv;                                \
    } } while (0)

    STAGE_TW(twA, kt0);
    __syncthreads();

    #pragma unroll
    for (int i8 = 0; i8 < 8; i8 += 2) {
        STAGE_TW(twB, kt0 + i8 + 1);
        COMPUTE(twA, kt0 + i8);
        __syncthreads();
        if (i8 + 2 < 8) STAGE_TW(twA, kt0 + i8 + 2);
        COMPUTE(twB, kt0 + i8 + 1);
        __syncthreads();
    }
#undef STAGE_TW
#undef COMPUTE

    #pragma unroll
    for (int off = 32; off > 0; off >>= 1) {
        s1 += __shfl_down(s1, off);
        s2 += __shfl_down(s2, off);
    }
    if (l == 0) {
        atomicAdd(&sacc[c0 + lc], s1);
        atomicAdd(&sacc[NCH + c0 + lc], s2);
    }
}

__global__ void finalize(const float* __restrict__ s, float* __restrict__ out) {
    int t = threadIdx.x;
    float v = 0.f;
    if (t < NCH) {
        float s1 = s[t], s2 = s[NCH + t];
        v = (s2 != 0.f) ? (s1 * s1) / s2 : 0.f;
    }
    for (int off = 32; off > 0; off >>= 1) v += __shfl_down(v, off);
    if (t == 0) out[0] = 24.0f - 0.5f * v / 261121.0f;
}

// ---------------- launch ----------------
extern "C" void kernel_launch(void* const* d_in, const int* in_sizes, int n_in,
                              void* d_out, int out_size, void* d_ws, size_t ws_size,
                              hipStream_t stream) {
    const float* recon  = (const float*)d_in[0];
    const float* target = (const float*)d_in[1];
    float* out = (float*)d_out;
    char* ws = (char*)d_ws;

    const size_t OFF_W2F = 0;                        // 524288 B
    const size_t OFF_S   = OFF_W2F + 524288;         // 512 B
    const size_t OFF_X1  = OFF_S + 512;

    u16*   w2f  = (u16*)(ws + OFF_W2F);
    float* sacc = (float*)(ws + OFF_S);
    u16*   x1t  = (u16*)(ws + OFF_X1);

    const size_t perch = 4ull * 65536 * 2;           // 512 KiB per channel
    size_t avail = (ws_size > OFF_X1) ? ws_size - OFF_X1 : 0;
    int chunk = (int)(avail / perch);
    if (chunk > NCH) chunk = NCH;
    if (chunk < 1) chunk = 1;

    setup<<<dim3(1024), dim3(256), 0, stream>>>(w2f, sacc);

    for (int c0 = 0; c0 < NCH; c0 += chunk) {
        int cc = (NCH - c0 < chunk) ? (NCH - c0) : chunk;
        stage1<<<dim3(16 * cc), dim3(256), 0, stream>>>(target, recon, w2f, x1t, c0);
        stage2<<<dim3(16 * cc), dim3(256), 0, stream>>>(x1t, w2f, sacc, c0, cc);
    }
    finalize<<<dim3(1), dim3(64), 0, stream>>>(sacc, out);
}

// Round 16
// 71.131 us; speedup vs baseline: 1.2120x; 1.2120x over previous
//
#include <hip/hip_runtime.h>
#include <math.h>

// AWLoss closed-form: f = 24 - (0.5/511^2) * sum_c S1_c^2 / S2_c
// S1 = sum wgt*Re(F), S2 = sum wgt*|F|^2 over half-spectrum k1 in [0,511),
// k2 in [0,256), wgt = 1 for k2==0 else 2, F = conj(X)Y / |X|^2
// (1e-9 pre-whitening is < 1e-12 relative to |X|^2 ~ 1e4 -> dropped).
// X = DFT2(pad(target)), Y = DFT2(pad(recon)), pad offset 127.
//
// Round-16: A/B experiment on the register allocator. stage2 = EXACT R6/R7
// structure (wave-task (ch,t), x1t frags pinned "+v", explicit 2-deep twiddle
// double-buffer streamed from L2, x1t read ONCE) + amdgpu_waves_per_eu(1,1):
// the 512-VGPR budget the design always needed (~300) but never got --
// R6/R7/R12 all capped at <=180 and serialized the 16-load stream (42us).
// R15's ktq split re-read x1t 4x (FETCH 50MB) -> reverted entirely.
// stage1/setup/finalize: exact R12 (best total, 61.2us).

#define NCH 48
#define PADOFF 127
#define TWO_PI_F 6.283185307179586f

typedef float f32x4 __attribute__((ext_vector_type(4)));
typedef short s16x8 __attribute__((ext_vector_type(8)));
typedef unsigned short u16;

union frag_u { u16 u[8]; s16x8 v; };

__device__ __forceinline__ u16 f2bf(float f) {
    union { float f; unsigned u; } x; x.f = f;
    unsigned r = x.u + 0x7FFFu + ((x.u >> 16) & 1u);
    return (u16)(r >> 16);
}

#define MFMA16(A, B, C) __builtin_amdgcn_mfma_f32_16x16x32_bf16(A, B, C, 0, 0, 0)

// ---------------- setup: twiddle fragment table + acc zero ----------------
// w2f : fragments [kt(32)][c(2)][kk(8)][lane(64)][j(8)] bf16
//       element: tw((16kt + (l&15)) * (32kk + 8(l>>4) + j + 127) mod 511),
//       c=0 cos, c=1 sin; rows k1>=511 zeroed.
__global__ __launch_bounds__(256) void setup(u16* __restrict__ w2f,
                                             float* __restrict__ sacc) {
    __shared__ float cs[511], sn[511];
    int tid = threadIdx.x;
    for (int i = tid; i < 511; i += 256) {
        float a = -TWO_PI_F * (float)i / 511.0f;
        cs[i] = cosf(a);
        sn[i] = sinf(a);
    }
    __syncthreads();

    int i = blockIdx.x * 256 + tid;      // i < 262144
    int j = i & 7, l = (i >> 3) & 63, kk = (i >> 9) & 7;
    int c = (i >> 12) & 1, kt = i >> 13;
    int k1 = 16 * kt + (l & 15);
    u16 v = 0;
    if (k1 < 511) {
        int n = 32 * kk + 8 * (l >> 4) + j;
        int p = (k1 * (n + PADOFF)) % 511;
        v = f2bf(c ? sn[p] : cs[p]);
    }
    w2f[i] = v;
    if (blockIdx.x == 0 && tid < 2 * NCH) sacc[tid] = 0.0f;
}

// ---------------- stage 1: DFT along W (exact R12 version) ----------------
__global__ __launch_bounds__(256, 2) void stage1(const float* __restrict__ target,
                                                 const float* __restrict__ recon,
                                                 const u16* __restrict__ w2f,
                                                 u16* __restrict__ x1t,
                                                 int c0) {
    int tid = threadIdx.x;
    int w = tid >> 6, l = tid & 63;
    int lm = l & 15, lh = l >> 4;
    int h   = blockIdx.x & 1;
    int q   = (blockIdx.x >> 1) & 3;
    int imgl = blockIdx.x >> 3;          // [0, 2cc)
    int lc = imgl >> 1;
    int tsel = imgl & 1;
    const float* src = (tsel == 0 ? target : recon) + (size_t)(c0 + lc) * 65536;
    int r0 = 64 * q;

    __shared__ u16 lin[16384];           // 32 KiB: [(s*8+kk)*512 + l*8]

    {
        int row = tid >> 2;              // 0..63
        int cg  = tid & 3;
        const float* rp = src + (size_t)(r0 + row) * 256 + cg * 64;
        float4 v[16];
        #pragma unroll
        for (int i = 0; i < 16; ++i) v[i] = *(const float4*)(rp + 4 * i);
        u16 b[64];
        #pragma unroll
        for (int i = 0; i < 16; ++i) {
            b[4*i]   = f2bf(v[i].x); b[4*i+1] = f2bf(v[i].y);
            b[4*i+2] = f2bf(v[i].z); b[4*i+3] = f2bf(v[i].w);
        }
        int s = row >> 4, lmw = row & 15;
        #pragma unroll
        for (int i2 = 0; i2 < 8; ++i2) {
            int col0 = cg * 64 + i2 * 8;
            int kk = col0 >> 5, lhw = (col0 >> 3) & 3;
            u16* dst = &lin[((s * 8 + kk) * 512) + (lhw * 16 + lmw) * 8];
            *(s16x8*)dst = *(const s16x8*)&b[i2 * 8];
        }
    }

    int t0 = 8 * h + 2 * w;
    s16x8 tw00[8], tw01[8], tw10[8], tw11[8];
    {
        const u16* p0 = w2f + (size_t)t0 * 8192 + l * 8;
        const u16* p1 = w2f + (size_t)(t0 + 1) * 8192 + l * 8;
        #pragma unroll
        for (int kk = 0; kk < 8; ++kk) {
            tw00[kk] = *(const s16x8*)(p0 + kk * 512);
            tw01[kk] = *(const s16x8*)(p0 + 4096 + kk * 512);
            tw10[kk] = *(const s16x8*)(p1 + kk * 512);
            tw11[kk] = *(const s16x8*)(p1 + 4096 + kk * 512);
        }
    }
    __syncthreads();

    f32x4 a00[4], a01[4], a10[4], a11[4];
    #pragma unroll
    for (int s = 0; s < 4; ++s) {
        a00[s] = (f32x4){0,0,0,0}; a01[s] = (f32x4){0,0,0,0};
        a10[s] = (f32x4){0,0,0,0}; a11[s] = (f32x4){0,0,0,0};
    }
    #pragma unroll
    for (int kk = 0; kk < 8; ++kk) {
        s16x8 af[4];
        #pragma unroll
        for (int s = 0; s < 4; ++s)
            af[s] = *(const s16x8*)&lin[((s * 8 + kk) * 512) + l * 8];
        #pragma unroll
        for (int s = 0; s < 4; ++s) {
            a00[s] = MFMA16(af[s], tw00[kk], a00[s]);
            a01[s] = MFMA16(af[s], tw01[kk], a01[s]);
            a10[s] = MFMA16(af[s], tw10[kk], a10[s]);
            a11[s] = MFMA16(af[s], tw11[kk], a11[s]);
        }
    }

    u16* chdst = x1t + (size_t)(lc * 4 + tsel * 2) * 65536;
    #pragma unroll
    for (int s = 0; s < 4; ++s) {
        size_t off0 = (size_t)(16 * t0 + lm) * 256 + r0 + 16 * s + 4 * lh;
        size_t off1 = off0 + 4096;
        ushort4 o;
        o.x = f2bf(a00[s][0]); o.y = f2bf(a00[s][1]);
        o.z = f2bf(a00[s][2]); o.w = f2bf(a00[s][3]);
        *(ushort4*)(chdst + off0) = o;
        o.x = f2bf(a01[s][0]); o.y = f2bf(a01[s][1]);
        o.z = f2bf(a01[s][2]); o.w = f2bf(a01[s][3]);
        *(ushort4*)(chdst + 65536 + off0) = o;
        o.x = f2bf(a10[s][0]); o.y = f2bf(a10[s][1]);
        o.z = f2bf(a10[s][2]); o.w = f2bf(a10[s][3]);
        *(ushort4*)(chdst + off1) = o;
        o.x = f2bf(a11[s][0]); o.y = f2bf(a11[s][1]);
        o.z = f2bf(a11[s][2]); o.w = f2bf(a11[s][3]);
        *(ushort4*)(chdst + 65536 + off1) = o;
    }
}

// ---------------- stage 2: frag-stationary + streamed twiddles (R7 form) ----------------
// grid = cc*4 blocks x 4 waves; wave task = (lc, t). x1t read ONCE into 128
// pinned VGPRs; twiddles double-buffered in VGPRs, streamed from L2 (all 4
// waves share addresses -> L1 broadcast). amdgpu_waves_per_eu(1,1) grants the
// 512-VGPR budget so the DB can actually materialize (~300 VGPR needed).
__global__ __launch_bounds__(256)
__attribute__((amdgpu_waves_per_eu(1, 1)))
void stage2(const u16* __restrict__ x1t,
            const u16* __restrict__ w2f,
            float* __restrict__ sacc,
            int c0, int cc) {
    int tid = threadIdx.x;
    int w = tid >> 6, l = tid & 63;
    int lm = l & 15, lh = l >> 4;
    int task = blockIdx.x * 4 + w;      // [0, cc*16)
    int lc = task >> 4;
    int t  = task & 15;

    const u16* base = x1t + (size_t)(4 * lc) * 65536;   // planes Xr,Xi,Yr,Yi
    size_t roff = (size_t)(16 * t + lm) * 256 + 8 * lh;

    s16x8 ar[8], ai[8], br[8], bi[8];
    #pragma unroll
    for (int kk = 0; kk < 8; ++kk) {
        size_t off = roff + 32 * kk;
        ar[kk] = *(const s16x8*)(base + off);
        ai[kk] = *(const s16x8*)(base + 65536 + off);
        br[kk] = *(const s16x8*)(base + 131072 + off);
        bi[kk] = *(const s16x8*)(base + 196608 + off);
    }
    #pragma unroll
    for (int kk = 0; kk < 8; ++kk)
        asm volatile("" : "+v"(ar[kk]), "+v"(ai[kk]), "+v"(br[kk]), "+v"(bi[kk]));

    int k2 = 16 * t + lm;
    float wgt = (k2 == 0) ? 1.f : 2.f;
    float s1 = 0.f, s2 = 0.f;

#define LOADW(WR, WI, KT) do {                                              \
    const u16* wp_ = w2f + (size_t)(KT) * 8192 + l * 8;                     \
    _Pragma("unroll")                                                       \
    for (int kk = 0; kk < 8; ++kk) {                                        \
        WR[kk] = *(const s16x8*)(wp_ + kk * 512);                           \
        WI[kk] = *(const s16x8*)(wp_ + 4096 + kk * 512);                    \
    } } while (0)

#define COMPUTE(WR, WI, KT) do {                                            \
    f32x4 crr = {0,0,0,0}, cii = {0,0,0,0}, cri = {0,0,0,0}, cir = {0,0,0,0}; \
    f32x4 drr = {0,0,0,0}, dii = {0,0,0,0}, dri = {0,0,0,0}, dir = {0,0,0,0}; \
    _Pragma("unroll")                                                       \
    for (int kk = 0; kk < 8; ++kk) {                                        \
        crr = MFMA16(WR[kk], ar[kk], crr);                                  \
        cii = MFMA16(WI[kk], ai[kk], cii);                                  \
        cri = MFMA16(WR[kk], ai[kk], cri);                                  \
        cir = MFMA16(WI[kk], ar[kk], cir);                                  \
        drr = MFMA16(WR[kk], br[kk], drr);                                  \
        dii = MFMA16(WI[kk], bi[kk], dii);                                  \
        dri = MFMA16(WR[kk], bi[kk], dri);                                  \
        dir = MFMA16(WI[kk], br[kk], dir);                                  \
    }                                                                       \
    _Pragma("unroll")                                                       \
    for (int r = 0; r < 4; ++r) {                                           \
        int k1_ = 16 * (KT) + 4 * lh + r;                                   \
        float wg2 = (k1_ < 511) ? wgt : 0.f;                                \
        float Xr = crr[r] - cii[r], Xi = cri[r] + cir[r];                   \
        float Yr = drr[r] - dii[r], Yi = dri[r] + dir[r];                   \
        float Pr = Xr * Yr + Xi * Yi;                                       \
        float Pi = Xr * Yi - Xi * Yr;                                       \
        float Q  = Xr * Xr + Xi * Xi;                                       \
        float inv = 1.0f / (Q * Q + 1e-30f);                                \
        s1 += wg2 * Pr * Q * inv;                                           \
        s2 += wg2 * (Pr * Pr + Pi * Pi) * inv;                              \
    } } while (0)

    s16x8 wrA[8], wiA[8], wrB[8], wiB[8];
    LOADW(wrA, wiA, 0);
    for (int kt = 0; kt < 32; kt += 2) {
        LOADW(wrB, wiB, kt + 1);
        COMPUTE(wrA, wiA, kt);
        if (kt + 2 < 32) LOADW(wrA, wiA, kt + 2);
        COMPUTE(wrB, wiB, kt + 1);
    }
#undef LOADW
#undef COMPUTE

    #pragma unroll
    for (int off = 32; off > 0; off >>= 1) {
        s1 += __shfl_down(s1, off);
        s2 += __shfl_down(s2, off);
    }
    if (l == 0) {
        atomicAdd(&sacc[c0 + lc], s1);
        atomicAdd(&sacc[NCH + c0 + lc], s2);
    }
}

__global__ void finalize(const float* __restrict__ s, float* __restrict__ out) {
    int t = threadIdx.x;
    float v = 0.f;
    if (t < NCH) {
        float s1 = s[t], s2 = s[NCH + t];
        v = (s2 != 0.f) ? (s1 * s1) / s2 : 0.f;
    }
    for (int off = 32; off > 0; off >>= 1) v += __shfl_down(v, off);
    if (t == 0) out[0] = 24.0f - 0.5f * v / 261121.0f;
}

// ---------------- launch ----------------
extern "C" void kernel_launch(void* const* d_in, const int* in_sizes, int n_in,
                              void* d_out, int out_size, void* d_ws, size_t ws_size,
                              hipStream_t stream) {
    const float* recon  = (const float*)d_in[0];
    const float* target = (const float*)d_in[1];
    float* out = (float*)d_out;
    char* ws = (char*)d_ws;

    const size_t OFF_W2F = 0;                        // 524288 B
    const size_t OFF_S   = OFF_W2F + 524288;         // 512 B
    const size_t OFF_X1  = OFF_S + 512;

    u16*   w2f  = (u16*)(ws + OFF_W2F);
    float* sacc = (float*)(ws + OFF_S);
    u16*   x1t  = (u16*)(ws + OFF_X1);

    const size_t perch = 4ull * 65536 * 2;           // 512 KiB per channel
    size_t avail = (ws_size > OFF_X1) ? ws_size - OFF_X1 : 0;
    int chunk = (int)(avail / perch);
    if (chunk > NCH) chunk = NCH;
    if (chunk < 1) chunk = 1;

    setup<<<dim3(1024), dim3(256), 0, stream>>>(w2f, sacc);

    for (int c0 = 0; c0 < NCH; c0 += chunk) {
        int cc = (NCH - c0 < chunk) ? (NCH - c0) : chunk;
        stage1<<<dim3(16 * cc), dim3(256), 0, stream>>>(target, recon, w2f, x1t, c0);
        stage2<<<dim3(cc * 4), dim3(256), 0, stream>>>(x1t, w2f, sacc, c0, cc);
    }
    finalize<<<dim3(1), dim3(64), 0, stream>>>(sacc, out);
}

// Round 17
// 69.360 us; speedup vs baseline: 1.2430x; 1.0255x over previous
//
#include <hip/hip_runtime.h>
#include <math.h>

// AWLoss closed-form: f = 24 - (0.5/511^2) * sum_c S1_c^2 / S2_c
// S1 = sum wgt*Re(F), S2 = sum wgt*|F|^2 over half-spectrum k1 in [0,511),
// k2 in [0,256), wgt = 1 for k2==0 else 2, F = conj(X)Y / |X|^2
// (1e-9 pre-whitening is < 1e-12 relative to |X|^2 ~ 1e4 -> dropped).
// X = DFT2(pad(target)), Y = DFT2(pad(recon)), pad offset 127.
//
// Round-17: R16 + sched_barrier(0) fences in stage2's kt loop. R6/R7/R14/R16
// all ran 42.9us at VGPR=176 because the scheduler SINKS each twiddle load to
// just before its consuming MFMA (per-kk: 2 loads -> wait -> 8 MFMA, ~200cyc
// exposed each). The fences make sinking illegal: 16 loads of buffer B must
// issue before buffer A's 64-MFMA block, forcing the double buffer to be
// live (which is what the waves_per_eu(1,1) 512-reg budget is for).

#define NCH 48
#define PADOFF 127
#define TWO_PI_F 6.283185307179586f

typedef float f32x4 __attribute__((ext_vector_type(4)));
typedef short s16x8 __attribute__((ext_vector_type(8)));
typedef unsigned short u16;

union frag_u { u16 u[8]; s16x8 v; };

__device__ __forceinline__ u16 f2bf(float f) {
    union { float f; unsigned u; } x; x.f = f;
    unsigned r = x.u + 0x7FFFu + ((x.u >> 16) & 1u);
    return (u16)(r >> 16);
}

#define MFMA16(A, B, C) __builtin_amdgcn_mfma_f32_16x16x32_bf16(A, B, C, 0, 0, 0)

// ---------------- setup: twiddle fragment table + acc zero ----------------
// w2f : fragments [kt(32)][c(2)][kk(8)][lane(64)][j(8)] bf16
//       element: tw((16kt + (l&15)) * (32kk + 8(l>>4) + j + 127) mod 511),
//       c=0 cos, c=1 sin; rows k1>=511 zeroed.
__global__ __launch_bounds__(256) void setup(u16* __restrict__ w2f,
                                             float* __restrict__ sacc) {
    __shared__ float cs[511], sn[511];
    int tid = threadIdx.x;
    for (int i = tid; i < 511; i += 256) {
        float a = -TWO_PI_F * (float)i / 511.0f;
        cs[i] = cosf(a);
        sn[i] = sinf(a);
    }
    __syncthreads();

    int i = blockIdx.x * 256 + tid;      // i < 262144
    int j = i & 7, l = (i >> 3) & 63, kk = (i >> 9) & 7;
    int c = (i >> 12) & 1, kt = i >> 13;
    int k1 = 16 * kt + (l & 15);
    u16 v = 0;
    if (k1 < 511) {
        int n = 32 * kk + 8 * (l >> 4) + j;
        int p = (k1 * (n + PADOFF)) % 511;
        v = f2bf(c ? sn[p] : cs[p]);
    }
    w2f[i] = v;
    if (blockIdx.x == 0 && tid < 2 * NCH) sacc[tid] = 0.0f;
}

// ---------------- stage 1: DFT along W (exact R12 version) ----------------
__global__ __launch_bounds__(256, 2) void stage1(const float* __restrict__ target,
                                                 const float* __restrict__ recon,
                                                 const u16* __restrict__ w2f,
                                                 u16* __restrict__ x1t,
                                                 int c0) {
    int tid = threadIdx.x;
    int w = tid >> 6, l = tid & 63;
    int lm = l & 15, lh = l >> 4;
    int h   = blockIdx.x & 1;
    int q   = (blockIdx.x >> 1) & 3;
    int imgl = blockIdx.x >> 3;          // [0, 2cc)
    int lc = imgl >> 1;
    int tsel = imgl & 1;
    const float* src = (tsel == 0 ? target : recon) + (size_t)(c0 + lc) * 65536;
    int r0 = 64 * q;

    __shared__ u16 lin[16384];           // 32 KiB: [(s*8+kk)*512 + l*8]

    {
        int row = tid >> 2;              // 0..63
        int cg  = tid & 3;
        const float* rp = src + (size_t)(r0 + row) * 256 + cg * 64;
        float4 v[16];
        #pragma unroll
        for (int i = 0; i < 16; ++i) v[i] = *(const float4*)(rp + 4 * i);
        u16 b[64];
        #pragma unroll
        for (int i = 0; i < 16; ++i) {
            b[4*i]   = f2bf(v[i].x); b[4*i+1] = f2bf(v[i].y);
            b[4*i+2] = f2bf(v[i].z); b[4*i+3] = f2bf(v[i].w);
        }
        int s = row >> 4, lmw = row & 15;
        #pragma unroll
        for (int i2 = 0; i2 < 8; ++i2) {
            int col0 = cg * 64 + i2 * 8;
            int kk = col0 >> 5, lhw = (col0 >> 3) & 3;
            u16* dst = &lin[((s * 8 + kk) * 512) + (lhw * 16 + lmw) * 8];
            *(s16x8*)dst = *(const s16x8*)&b[i2 * 8];
        }
    }

    int t0 = 8 * h + 2 * w;
    s16x8 tw00[8], tw01[8], tw10[8], tw11[8];
    {
        const u16* p0 = w2f + (size_t)t0 * 8192 + l * 8;
        const u16* p1 = w2f + (size_t)(t0 + 1) * 8192 + l * 8;
        #pragma unroll
        for (int kk = 0; kk < 8; ++kk) {
            tw00[kk] = *(const s16x8*)(p0 + kk * 512);
            tw01[kk] = *(const s16x8*)(p0 + 4096 + kk * 512);
            tw10[kk] = *(const s16x8*)(p1 + kk * 512);
            tw11[kk] = *(const s16x8*)(p1 + 4096 + kk * 512);
        }
    }
    __syncthreads();

    f32x4 a00[4], a01[4], a10[4], a11[4];
    #pragma unroll
    for (int s = 0; s < 4; ++s) {
        a00[s] = (f32x4){0,0,0,0}; a01[s] = (f32x4){0,0,0,0};
        a10[s] = (f32x4){0,0,0,0}; a11[s] = (f32x4){0,0,0,0};
    }
    #pragma unroll
    for (int kk = 0; kk < 8; ++kk) {
        s16x8 af[4];
        #pragma unroll
        for (int s = 0; s < 4; ++s)
            af[s] = *(const s16x8*)&lin[((s * 8 + kk) * 512) + l * 8];
        #pragma unroll
        for (int s = 0; s < 4; ++s) {
            a00[s] = MFMA16(af[s], tw00[kk], a00[s]);
            a01[s] = MFMA16(af[s], tw01[kk], a01[s]);
            a10[s] = MFMA16(af[s], tw10[kk], a10[s]);
            a11[s] = MFMA16(af[s], tw11[kk], a11[s]);
        }
    }

    u16* chdst = x1t + (size_t)(lc * 4 + tsel * 2) * 65536;
    #pragma unroll
    for (int s = 0; s < 4; ++s) {
        size_t off0 = (size_t)(16 * t0 + lm) * 256 + r0 + 16 * s + 4 * lh;
        size_t off1 = off0 + 4096;
        ushort4 o;
        o.x = f2bf(a00[s][0]); o.y = f2bf(a00[s][1]);
        o.z = f2bf(a00[s][2]); o.w = f2bf(a00[s][3]);
        *(ushort4*)(chdst + off0) = o;
        o.x = f2bf(a01[s][0]); o.y = f2bf(a01[s][1]);
        o.z = f2bf(a01[s][2]); o.w = f2bf(a01[s][3]);
        *(ushort4*)(chdst + 65536 + off0) = o;
        o.x = f2bf(a10[s][0]); o.y = f2bf(a10[s][1]);
        o.z = f2bf(a10[s][2]); o.w = f2bf(a10[s][3]);
        *(ushort4*)(chdst + off1) = o;
        o.x = f2bf(a11[s][0]); o.y = f2bf(a11[s][1]);
        o.z = f2bf(a11[s][2]); o.w = f2bf(a11[s][3]);
        *(ushort4*)(chdst + 65536 + off1) = o;
    }
}

// ---------------- stage 2: frag-stationary + fenced twiddle pipeline ----------------
// grid = cc*4 blocks x 4 waves; wave task = (lc, t). x1t read ONCE into 128
// pinned VGPRs; twiddles double-buffered in VGPRs with sched_barrier(0)
// fences so the scheduler cannot sink the loads to their uses.
__global__ __launch_bounds__(256)
__attribute__((amdgpu_waves_per_eu(1, 1)))
void stage2(const u16* __restrict__ x1t,
            const u16* __restrict__ w2f,
            float* __restrict__ sacc,
            int c0, int cc) {
    int tid = threadIdx.x;
    int w = tid >> 6, l = tid & 63;
    int lm = l & 15, lh = l >> 4;
    int task = blockIdx.x * 4 + w;      // [0, cc*16)
    int lc = task >> 4;
    int t  = task & 15;

    const u16* base = x1t + (size_t)(4 * lc) * 65536;   // planes Xr,Xi,Yr,Yi
    size_t roff = (size_t)(16 * t + lm) * 256 + 8 * lh;

    s16x8 ar[8], ai[8], br[8], bi[8];
    #pragma unroll
    for (int kk = 0; kk < 8; ++kk) {
        size_t off = roff + 32 * kk;
        ar[kk] = *(const s16x8*)(base + off);
        ai[kk] = *(const s16x8*)(base + 65536 + off);
        br[kk] = *(const s16x8*)(base + 131072 + off);
        bi[kk] = *(const s16x8*)(base + 196608 + off);
    }
    #pragma unroll
    for (int kk = 0; kk < 8; ++kk)
        asm volatile("" : "+v"(ar[kk]), "+v"(ai[kk]), "+v"(br[kk]), "+v"(bi[kk]));

    int k2 = 16 * t + lm;
    float wgt = (k2 == 0) ? 1.f : 2.f;
    float s1 = 0.f, s2 = 0.f;

#define LOADW(WR, WI, KT) do {                                              \
    const u16* wp_ = w2f + (size_t)(KT) * 8192 + l * 8;                     \
    _Pragma("unroll")                                                       \
    for (int kk = 0; kk < 8; ++kk) {                                        \
        WR[kk] = *(const s16x8*)(wp_ + kk * 512);                           \
        WI[kk] = *(const s16x8*)(wp_ + 4096 + kk * 512);                    \
    } } while (0)

#define COMPUTE(WR, WI, KT) do {                                            \
    f32x4 crr = {0,0,0,0}, cii = {0,0,0,0}, cri = {0,0,0,0}, cir = {0,0,0,0}; \
    f32x4 drr = {0,0,0,0}, dii = {0,0,0,0}, dri = {0,0,0,0}, dir = {0,0,0,0}; \
    _Pragma("unroll")                                                       \
    for (int kk = 0; kk < 8; ++kk) {                                        \
        crr = MFMA16(WR[kk], ar[kk], crr);                                  \
        cii = MFMA16(WI[kk], ai[kk], cii);                                  \
        cri = MFMA16(WR[kk], ai[kk], cri);                                  \
        cir = MFMA16(WI[kk], ar[kk], cir);                                  \
        drr = MFMA16(WR[kk], br[kk], drr);                                  \
        dii = MFMA16(WI[kk], bi[kk], dii);                                  \
        dri = MFMA16(WR[kk], bi[kk], dri);                                  \
        dir = MFMA16(WI[kk], br[kk], dir);                                  \
    }                                                                       \
    _Pragma("unroll")                                                       \
    for (int r = 0; r < 4; ++r) {                                           \
        int k1_ = 16 * (KT) + 4 * lh + r;                                   \
        float wg2 = (k1_ < 511) ? wgt : 0.f;                                \
        float Xr = crr[r] - cii[r], Xi = cri[r] + cir[r];                   \
        float Yr = drr[r] - dii[r], Yi = dri[r] + dir[r];                   \
        float Pr = Xr * Yr + Xi * Yi;                                       \
        float Pi = Xr * Yi - Xi * Yr;                                       \
        float Q  = Xr * Xr + Xi * Xi;                                       \
        float inv = 1.0f / (Q * Q + 1e-30f);                                \
        s1 += wg2 * Pr * Q * inv;                                           \
        s2 += wg2 * (Pr * Pr + Pi * Pi) * inv;                              \
    } } while (0)

    s16x8 wrA[8], wiA[8], wrB[8], wiB[8];
    LOADW(wrA, wiA, 0);
    for (int kt = 0; kt < 32; kt += 2) {
        LOADW(wrB, wiB, kt + 1);
        __builtin_amdgcn_sched_barrier(0);   // B loads issue BEFORE A compute
        COMPUTE(wrA, wiA, kt);
        __builtin_amdgcn_sched_barrier(0);
        if (kt + 2 < 32) LOADW(wrA, wiA, kt + 2);
        __builtin_amdgcn_sched_barrier(0);   // A loads issue BEFORE B compute
        COMPUTE(wrB, wiB, kt + 1);
        __builtin_amdgcn_sched_barrier(0);
    }
#undef LOADW
#undef COMPUTE

    #pragma unroll
    for (int off = 32; off > 0; off >>= 1) {
        s1 += __shfl_down(s1, off);
        s2 += __shfl_down(s2, off);
    }
    if (l == 0) {
        atomicAdd(&sacc[c0 + lc], s1);
        atomicAdd(&sacc[NCH + c0 + lc], s2);
    }
}

__global__ void finalize(const float* __restrict__ s, float* __restrict__ out) {
    int t = threadIdx.x;
    float v = 0.f;
    if (t < NCH) {
        float s1 = s[t], s2 = s[NCH + t];
        v = (s2 != 0.f) ? (s1 * s1) / s2 : 0.f;
    }
    for (int off = 32; off > 0; off >>= 1) v += __shfl_down(v, off);
    if (t == 0) out[0] = 24.0f - 0.5f * v / 261121.0f;
}

// ---------------- launch ----------------
extern "C" void kernel_launch(void* const* d_in, const int* in_sizes, int n_in,
                              void* d_out, int out_size, void* d_ws, size_t ws_size,
                              hipStream_t stream) {
    const float* recon  = (const float*)d_in[0];
    const float* target = (const float*)d_in[1];
    float* out = (float*)d_out;
    char* ws = (char*)d_ws;

    const size_t OFF_W2F = 0;                        // 524288 B
    const size_t OFF_S   = OFF_W2F + 524288;         // 512 B
    const size_t OFF_X1  = OFF_S + 512;

    u16*   w2f  = (u16*)(ws + OFF_W2F);
    float* sacc = (float*)(ws + OFF_S);
    u16*   x1t  = (u16*)(ws + OFF_X1);

    const size_t perch = 4ull * 65536 * 2;           // 512 KiB per channel
    size_t avail = (ws_size > OFF_X1) ? ws_size - OFF_X1 : 0;
    int chunk = (int)(avail / perch);
    if (chunk > NCH) chunk = NCH;
    if (chunk < 1) chunk = 1;

    setup<<<dim3(1024), dim3(256), 0, stream>>>(w2f, sacc);

    for (int c0 = 0; c0 < NCH; c0 += chunk) {
        int cc = (NCH - c0 < chunk) ? (NCH - c0) : chunk;
        stage1<<<dim3(16 * cc), dim3(256), 0, stream>>>(target, recon, w2f, x1t, c0);
        stage2<<<dim3(cc * 4), dim3(256), 0, stream>>>(x1t, w2f, sacc, c0, cc);
    }
    finalize<<<dim3(1), dim3(64), 0, stream>>>(sacc, out);
}